// Round 5
// baseline (8789.272 us; speedup 1.0000x reference)
//
#include <hip/hip_runtime.h>
#include <cstdint>
#include <cstddef>

typedef short short8 __attribute__((ext_vector_type(8)));
typedef float f32x4 __attribute__((ext_vector_type(4)));
typedef unsigned int u32;
typedef unsigned short u16;

#define DEV __device__ __forceinline__

// problem dims
constexpr int BB = 64, TT = 512, IN0 = 128, H1 = 256, H2 = 512;
constexpr size_t OUT_ELEMS = (size_t)BB * TT * IN0;  // 4194304

constexpr size_t ALB(size_t x) { return (x + 255) & ~(size_t)255; }
constexpr size_t A16(size_t x) { return (x + 15) & ~(size_t)15; }

// ---------------- workspace layout (bytes) ----------------
constexpr size_t XS  = (size_t)BB * TT * IN0;
constexpr size_t Y1S = (size_t)BB * TT * H1;
constexpr size_t HBR = (size_t)2 * BB * H2 * 2;                 // one hb plane (sized for H2)
constexpr size_t OFF_CNT  = 0;                                  // u32 counters: e1@0 e2@64 d1@128 d2@192 (256B apart)
constexpr size_t OFF_XHI  = 4096;
constexpr size_t OFF_XLO  = ALB(OFF_XHI + XS * 2);
constexpr size_t OFF_Y1HI = ALB(OFF_XLO + XS * 2);
constexpr size_t OFF_Y1LO = ALB(OFF_Y1HI + Y1S * 2);
constexpr size_t OFF_Y3HI = ALB(OFF_Y1LO + Y1S * 2);
constexpr size_t OFF_Y3LO = ALB(OFF_Y3HI + Y1S * 2);
constexpr size_t OFF_HB1HI = ALB(OFF_Y3LO + Y1S * 2);           // 4 contiguous hb planes
constexpr size_t OFF_HB1LO = OFF_HB1HI + HBR;
constexpr size_t OFF_HB2HI = OFF_HB1LO + HBR;
constexpr size_t OFF_HB2LO = OFF_HB2HI + HBR;
constexpr size_t OFF_H0HI = ALB(OFF_HB2LO + HBR);
constexpr size_t OFF_H0LO = ALB(OFF_H0HI + (size_t)BB * H2 * 2);
constexpr size_t OFF_H0F  = ALB(OFF_H0LO + (size_t)BB * H2 * 2);
constexpr size_t OFF_WE1  = ALB(OFF_H0F + (size_t)BB * H2 * 4);
constexpr size_t W_E1S = (size_t)4 * H1 * (IN0 + H1) * 2;       // shorts incl. both planes
constexpr size_t OFF_WE2  = ALB(OFF_WE1 + W_E1S * 2);
constexpr size_t W_E2S = (size_t)4 * H2 * (H1 + H2) * 2;
constexpr size_t OFF_WD1  = ALB(OFF_WE2 + W_E2S * 2);
constexpr size_t W_D1S = (size_t)4 * H1 * (H2 + H1) * 2;
constexpr size_t OFF_WD2  = ALB(OFF_WD1 + W_D1S * 2);

// ---------------- helpers ----------------
DEV void split32(float v, u16& hi, u16& lo) {
  u32 u = __builtin_bit_cast(u32, v);
  hi = (u16)(u >> 16);
  float hif = __builtin_bit_cast(float, u & 0xFFFF0000u);
  lo = (u16)(__builtin_bit_cast(u32, v - hif) >> 16);
}

DEV f32x4 mm(short8 a, short8 b, f32x4 c) {
  return __builtin_amdgcn_mfma_f32_16x16x32_bf16(a, b, c, 0, 0, 0);
}

DEV float sigm(float x) { return 1.f / (1.f + __expf(-x)); }
DEV float tanh_f(float x) { return 1.f - 2.f / (__expf(2.f * x) + 1.f); }

// Coherent (L1/L2-bypassing) ops — served at LLC, no fences needed.
DEV void ldg16c(short8& d, const short* p) {
  asm volatile("global_load_dwordx4 %0, %1, off sc0 sc1" : "=v"(d) : "v"(p));
}
DEV void stg4c(u32* p, u32 v) {
  asm volatile("global_store_dword %0, %1, off sc0 sc1" :: "v"(p), "v"(v) : "memory");
}

// group-issue N chunk pairs (2 dwordx4 each)
template<int N>
DEV void grp_issue(short8 (&h)[N], short8 (&l)[N], const short* ph, const short* pl) {
  #pragma unroll
  for (int i = 0; i < N; ++i) { ldg16c(h[i], ph + i * 32); ldg16c(l[i], pl + i * 32); }
}

#define TIE16(h, l) \
  "+v"(h[0]), "+v"(h[1]), "+v"(h[2]), "+v"(h[3]), "+v"(h[4]), "+v"(h[5]), "+v"(h[6]), "+v"(h[7]), \
  "+v"(l[0]), "+v"(l[1]), "+v"(l[2]), "+v"(l[3]), "+v"(l[4]), "+v"(l[5]), "+v"(l[6]), "+v"(l[7])

DEV void wt16_c0(short8 (&h)[8], short8 (&l)[8]) {
  asm volatile("s_waitcnt vmcnt(0)" : TIE16(h, l) :: "memory");
  __builtin_amdgcn_sched_barrier(0);
}
DEV void wt16_c8(short8 (&h)[8], short8 (&l)[8]) {
  asm volatile("s_waitcnt vmcnt(8)" : TIE16(h, l) :: "memory");
  __builtin_amdgcn_sched_barrier(0);
}
DEV void wt16_c16(short8 (&h)[8], short8 (&l)[8]) {
  asm volatile("s_waitcnt vmcnt(16)" : TIE16(h, l) :: "memory");
  __builtin_amdgcn_sched_barrier(0);
}
DEV void wt8_c0(short8 (&h)[4], short8 (&l)[4]) {
  asm volatile("s_waitcnt vmcnt(0)"
               : "+v"(h[0]), "+v"(h[1]), "+v"(h[2]), "+v"(h[3]),
                 "+v"(l[0]), "+v"(l[1]), "+v"(l[2]), "+v"(l[3]) :: "memory");
  __builtin_amdgcn_sched_barrier(0);
}

// Poll two monotone counter words until own >= othr and up >= uthr.
// All lanes load the SAME words -> one coalesced request per wave; values
// wave-uniform so the branch is uniform. s_sleep backoff keeps the counter
// line cool so producers' atomic adds land promptly.
DEV void poll2(const u32* own, u32 othr, const u32* up, u32 uthr) {
  while (true) {
    u32 a, b;
    asm volatile("global_load_dword %0, %2, off sc0 sc1\n\t"
                 "global_load_dword %1, %3, off sc0 sc1\n\t"
                 "s_waitcnt vmcnt(0)"
                 : "=v"(a), "=v"(b) : "v"(own), "v"(up) : "memory");
    if (a >= othr && b >= uthr) return;
    __builtin_amdgcn_s_sleep(2);
  }
}

template<int NTv>
DEV void store_tile(float* dst, const f32x4* acc, int lane, int wave, int RS_) {
  #pragma unroll
  for (int nt = 0; nt < NTv; ++nt)
    #pragma unroll
    for (int r = 0; r < 4; ++r)
      dst[(wave * 16 + (lane >> 4) * 4 + r) * RS_ + nt * 16 + (lane & 15)] = acc[nt][r];
}

template<int NTv, int PLANEv, int NCH>
DEV void mfma_grp(f32x4 (&acc)[NTv], const short8* ha, const short8* la,
                  int cbase, const short* wlds, int lane) {
  #pragma unroll
  for (int cc = 0; cc < NCH; ++cc) {
    const int c = cbase + cc;
    #pragma unroll
    for (int nt = 0; nt < NTv; ++nt) {
      const int fo = ((c * NTv + nt) * 64 + lane) * 8;
      short8 bh = *(const short8*)(wlds + fo);
      short8 bl = *(const short8*)(wlds + PLANEv + fo);
      acc[nt] = mm(ha[cc], bh, acc[nt]);
      acc[nt] = mm(la[cc], bh, acc[nt]);
      acc[nt] = mm(ha[cc], bl, acc[nt]);
    }
  }
}

// ---------------- prep kernels ----------------
__global__ void pack_x_k(const float* __restrict__ src, short* __restrict__ hp,
                         short* __restrict__ lp, size_t n) {
  for (size_t i = (size_t)blockIdx.x * blockDim.x + threadIdx.x; i < n;
       i += (size_t)gridDim.x * blockDim.x) {
    u16 hi, lo; split32(src[i], hi, lo);
    hp[i] = (short)hi; lp[i] = (short)lo;
  }
}

template<int In, int Hh, int P>
__global__ void prep_w(const float* __restrict__ wih, const float* __restrict__ whh,
                       short* __restrict__ dst) {
  constexpr int Jc = Hh / P, R = 4 * Jc, NT = R / 16, K = In + Hh;
  constexpr int NC32 = K / 32, PLANE = NC32 * NT * 512, WGS = 2 * PLANE;
  const size_t total = (size_t)P * PLANE;
  for (size_t s = (size_t)blockIdx.x * blockDim.x + threadIdx.x; s < total;
       s += (size_t)gridDim.x * blockDim.x) {
    int p   = (int)(s / PLANE);
    int r2  = (int)(s % PLANE);
    int c32 = r2 / (NT * 512);
    int r3  = r2 % (NT * 512);
    int nt  = r3 / 512;
    int sl  = r3 % 512;
    int lane = sl / 8, j = sl % 8;
    int n  = nt * 16 + (lane & 15);
    int g  = n / Jc, jl = n % Jc;
    int grow = g * Hh + p * Jc + jl;
    int k = c32 * 32 + (lane >> 4) * 8 + j;
    float v = (k < In) ? wih[(size_t)grow * In + k] : whh[(size_t)grow * Hh + (k - In)];
    u16 hi, lo; split32(v, hi, lo);
    dst[(size_t)p * WGS + r2]         = (short)hi;
    dst[(size_t)p * WGS + PLANE + r2] = (short)lo;
  }
}

// ---------------- persistent LSTM layer body ----------------
// Counter-sync, ping-pong depth 2. At step t a WG requires:
//   own counter >= P*t        (all peers finished step t-1 -> h(t) published,
//                              and buffer t+1 free for overwrite)
//   up  counter >= UP*(t+1)   (upstream finished step t -> y(t) published)
// After publishing its h slice it drains stores (vmcnt 0), barriers, and tid0
// does ONE relaxed agent-scope atomic add. All cross-WG data via sc0sc1 (LLC).
template<int In, int Hh, int P, int UP, bool CX, bool COHX, bool WY, bool WO, bool WH0>
DEV void lstm_body(int p, const short* __restrict__ wfrag, const float* __restrict__ bias,
                   const int* __restrict__ lengths,
                   const short* xhi, const short* xlo,
                   short* hbhi, short* hblo,
                   short* yhi, short* ylo, float* outp,
                   short* h0hi, short* h0lo, float* h0f,
                   u32* owncnt, const u32* upcnt, char* smem) {
  constexpr int Jc = Hh / P, R = 4 * Jc, NT = R / 16, K = In + Hh;
  constexpr int NC32 = K / 32, C0 = In / 32, HC = Hh / 32;
  constexpr int PLANE = NC32 * NT * 512, WGS = 2 * PLANE;
  constexpr int RS = R + 1;
  constexpr int JH = Jc / 2, NP = 64 * JH;
  static_assert(R % 16 == 0 && K % 32 == 0 && In % 32 == 0 && Jc % 2 == 0 && NP <= 256, "geometry");

  constexpr size_t SM_W = A16((size_t)WGS * 2);
  constexpr size_t SM_G = A16((size_t)64 * RS * 4);
  short* wlds  = (short*)smem;
  float* gates = (float*)(smem + SM_W);
  float* gx    = (float*)(smem + SM_W + SM_G);   // only when CX

  const int tid = threadIdx.x;
  const int lane = tid & 63, wave = tid >> 6;
  const int j0 = p * Jc;
  const int m = wave * 16 + (lane & 15);         // batch this lane supplies to A-frags
  const int klane = (lane >> 4) * 8;
  const size_t BH = (size_t)BB * Hh;

  // stage weights (linear copy; already in fragment order)
  {
    const uint4* src = (const uint4*)(wfrag + (size_t)p * WGS);
    uint4* dv = (uint4*)wlds;
    for (int i = tid; i < WGS / 8; i += 256) dv[i] = src[i];
  }

  // persistent per-thread recurrent state (one jl-pair of one batch)
  const bool actv = tid < NP;
  int b = 0, jl = 0, mylen = 0;
  float cc0 = 0.f, cc1 = 0.f, hh0 = 0.f, hh1 = 0.f;
  float bi0 = 0, bi1 = 0, bf0 = 0, bf1 = 0, bg0 = 0, bg1 = 0, bo0 = 0, bo1 = 0;
  if (actv) {
    b = tid / JH; jl = (tid % JH) * 2;
    mylen = lengths[b];
    bi0 = bias[0 * Hh + j0 + jl]; bi1 = bias[0 * Hh + j0 + jl + 1];
    bf0 = bias[1 * Hh + j0 + jl]; bf1 = bias[1 * Hh + j0 + jl + 1];
    bg0 = bias[2 * Hh + j0 + jl]; bg1 = bias[2 * Hh + j0 + jl + 1];
    bo0 = bias[3 * Hh + j0 + jl]; bo1 = bias[3 * Hh + j0 + jl + 1];
  }

  __syncthreads();  // wlds staged (CX prologue below reads it!)

  // constant input projection (decoder-1: dec_in = h0 for all valid t)
  if constexpr (CX) {
    f32x4 acc[NT];
    #pragma unroll
    for (int nt = 0; nt < NT; ++nt) acc[nt] = f32x4{0.f, 0.f, 0.f, 0.f};
    #pragma unroll
    for (int c = 0; c < C0; ++c) {
      size_t idx = (size_t)m * In + c * 32 + klane;
      short8 ah = *(const short8*)(xhi + idx);
      short8 al = *(const short8*)(xlo + idx);
      #pragma unroll
      for (int nt = 0; nt < NT; ++nt) {
        int fo = ((c * NT + nt) * 64 + lane) * 8;
        short8 bh = *(const short8*)(wlds + fo);
        short8 bl = *(const short8*)(wlds + PLANE + fo);
        acc[nt] = mm(ah, bh, acc[nt]);
        acc[nt] = mm(al, bh, acc[nt]);
        acc[nt] = mm(ah, bl, acc[nt]);
      }
    }
    store_tile<NT>(gx, acc, lane, wave, RS);
    __syncthreads();
  }

  for (int t = 0; t < TT; ++t) {
    const int cur = t & 1, nxt = cur ^ 1;
    if constexpr (UP > 0) poll2(owncnt, (u32)(P * t), upcnt, (u32)(UP * (t + 1)));
    else                  poll2(owncnt, (u32)(P * t), owncnt, (u32)(P * t));

    f32x4 acc[NT];
    #pragma unroll
    for (int nt = 0; nt < NT; ++nt) acc[nt] = f32x4{0.f, 0.f, 0.f, 0.f};

    const short* hph = hbhi + (size_t)cur * BH + (size_t)m * Hh + klane;
    const short* hpl = hblo + (size_t)cur * BH + (size_t)m * Hh + klane;

    if constexpr (!CX && !COHX) {
      // e1: plain cached x loads (input produced by a previous kernel)
      #pragma unroll
      for (int c = 0; c < C0; ++c) {
        size_t idx = ((size_t)m * TT + t) * In + c * 32 + klane;
        short8 ah = *(const short8*)(xhi + idx);
        short8 al = *(const short8*)(xlo + idx);
        #pragma unroll
        for (int nt = 0; nt < NT; ++nt) {
          int fo = ((c * NT + nt) * 64 + lane) * 8;
          short8 bh = *(const short8*)(wlds + fo);
          short8 bl = *(const short8*)(wlds + PLANE + fo);
          acc[nt] = mm(ah, bh, acc[nt]);
          acc[nt] = mm(al, bh, acc[nt]);
          acc[nt] = mm(ah, bl, acc[nt]);
        }
      }
    }

    if constexpr (COHX) {
      static_assert(C0 == 8, "cohx geometry");
      const short* pxh = xhi + ((size_t)m * TT + t) * In + klane;
      const short* pxl = xlo + ((size_t)m * TT + t) * In + klane;
      short8 xh[8], xl[8];
      grp_issue<8>(xh, xl, pxh, pxl);
      if constexpr (HC == 16) {       // e2
        short8 h1h[8], h1l[8];
        grp_issue<8>(h1h, h1l, hph, hpl);
        wt16_c16(xh, xl);
        mfma_grp<NT, PLANE, 8>(acc, xh, xl, 0, wlds, lane);
        short8 h2h[8], h2l[8];
        grp_issue<8>(h2h, h2l, hph + 256, hpl + 256);
        wt16_c16(h1h, h1l);
        mfma_grp<NT, PLANE, 8>(acc, h1h, h1l, C0, wlds, lane);
        wt16_c0(h2h, h2l);
        mfma_grp<NT, PLANE, 8>(acc, h2h, h2l, C0 + 8, wlds, lane);
      } else {                        // d2 (HC == 4)
        static_assert(HC == 4, "d2 geometry");
        short8 hh4[4], hl4[4];
        grp_issue<4>(hh4, hl4, hph, hpl);
        wt16_c8(xh, xl);
        mfma_grp<NT, PLANE, 8>(acc, xh, xl, 0, wlds, lane);
        wt8_c0(hh4, hl4);
        mfma_grp<NT, PLANE, 4>(acc, hh4, hl4, C0, wlds, lane);
      }
    } else {
      static_assert(HC == 8, "h geometry");
      short8 hh8[8], hl8[8];
      grp_issue<8>(hh8, hl8, hph, hpl);
      wt16_c0(hh8, hl8);
      mfma_grp<NT, PLANE, 8>(acc, hh8, hl8, C0, wlds, lane);
    }

    store_tile<NT>(gates, acc, lane, wave, RS);
    __syncthreads();

    if (actv) {
      const int gb = b * RS;
      float gi0 = gates[gb + 0 * Jc + jl] + bi0, gi1 = gates[gb + 0 * Jc + jl + 1] + bi1;
      float gf0 = gates[gb + 1 * Jc + jl] + bf0, gf1 = gates[gb + 1 * Jc + jl + 1] + bf1;
      float gg0 = gates[gb + 2 * Jc + jl] + bg0, gg1 = gates[gb + 2 * Jc + jl + 1] + bg1;
      float go0 = gates[gb + 3 * Jc + jl] + bo0, go1 = gates[gb + 3 * Jc + jl + 1] + bo1;
      if constexpr (CX) {
        gi0 += gx[gb + 0 * Jc + jl]; gi1 += gx[gb + 0 * Jc + jl + 1];
        gf0 += gx[gb + 1 * Jc + jl]; gf1 += gx[gb + 1 * Jc + jl + 1];
        gg0 += gx[gb + 2 * Jc + jl]; gg1 += gx[gb + 2 * Jc + jl + 1];
        go0 += gx[gb + 3 * Jc + jl]; go1 += gx[gb + 3 * Jc + jl + 1];
      }
      bool valid = t < mylen;
      float cn0 = sigm(gf0) * cc0 + sigm(gi0) * tanh_f(gg0);
      float hn0 = sigm(go0) * tanh_f(cn0);
      float cn1 = sigm(gf1) * cc1 + sigm(gi1) * tanh_f(gg1);
      float hn1 = sigm(go1) * tanh_f(cn1);
      if (valid) { cc0 = cn0; hh0 = hn0; cc1 = cn1; hh1 = hn1; }
      u16 p0h, p0l, p1h, p1l;
      split32(hh0, p0h, p0l); split32(hh1, p1h, p1l);
      u32 whi = (u32)p0h | ((u32)p1h << 16);
      u32 wlo = (u32)p0l | ((u32)p1l << 16);
      size_t wi = ((size_t)b * Hh + j0 + jl) >> 1;
      stg4c((u32*)(hbhi + (size_t)nxt * BH) + wi, whi);
      stg4c((u32*)(hblo + (size_t)nxt * BH) + wi, wlo);
      if constexpr (WY) {
        if (valid) {
          size_t yo = ((size_t)b * TT + t) * Hh + j0 + jl;
          stg4c((u32*)(yhi + yo), whi);
          stg4c((u32*)(ylo + yo), wlo);
        }
      }
      if constexpr (WO) {
        if (valid) {
          size_t oo = ((size_t)b * TT + t) * Hh + j0 + jl;
          outp[oo] = hh0; outp[oo + 1] = hh1;
        }
      }
    }
    asm volatile("s_waitcnt vmcnt(0)" ::: "memory");  // all publishes ack'd at LLC
    __syncthreads();
    if (tid == 0)
      __hip_atomic_fetch_add(owncnt, 1u, __ATOMIC_RELAXED, __HIP_MEMORY_SCOPE_AGENT);
  }

  if constexpr (WH0) {
    if (actv) {
      u16 p0h, p0l, p1h, p1l;
      split32(hh0, p0h, p0l); split32(hh1, p1h, p1l);
      size_t o = (size_t)b * Hh + j0 + jl;
      h0hi[o] = (short)p0h; h0hi[o + 1] = (short)p1h;
      h0lo[o] = (short)p0l; h0lo[o + 1] = (short)p1l;
      h0f[o] = hh0; h0f[o + 1] = hh1;
    }
  }
}

// ---------------- fused phase kernels ----------------
__global__ __launch_bounds__(256, 1) void phaseA_k(
    const short* we1, const float* e1b, const short* we2, const float* e2b,
    const int* lens, const short* xhi, const short* xlo,
    short* y1hi, short* y1lo,
    short* hb1hi, short* hb1lo, short* hb2hi, short* hb2lo,
    short* h0hi, short* h0lo, float* h0f, u32* cnt) {
  extern __shared__ char smem[];
  if (blockIdx.x < 32)
    lstm_body<IN0, H1, 32, 0, false, false, true, false, false>(
        blockIdx.x, we1, e1b, lens, xhi, xlo, hb1hi, hb1lo,
        y1hi, y1lo, nullptr, nullptr, nullptr, nullptr, cnt, nullptr, smem);
  else
    lstm_body<H1, H2, 64, 32, false, true, false, false, true>(
        blockIdx.x - 32, we2, e2b, lens, y1hi, y1lo, hb2hi, hb2lo,
        nullptr, nullptr, nullptr, h0hi, h0lo, h0f, cnt + 64, cnt, smem);
}

__global__ __launch_bounds__(256, 1) void phaseB_k(
    const short* wd1, const float* d1b, const short* wd2, const float* d2b,
    const int* lens, const short* h0hi_in, const short* h0lo_in,
    short* y3hi, short* y3lo,
    short* hb1hi, short* hb1lo, short* hb2hi, short* hb2lo,
    float* outp, u32* cnt) {
  extern __shared__ char smem[];
  if (blockIdx.x < 32)
    lstm_body<H2, H1, 32, 0, true, false, true, false, false>(
        blockIdx.x, wd1, d1b, lens, h0hi_in, h0lo_in, hb1hi, hb1lo,
        y3hi, y3lo, nullptr, nullptr, nullptr, nullptr, cnt + 128, nullptr, smem);
  else
    lstm_body<H1, IN0, 32, 32, false, true, false, true, false>(
        blockIdx.x - 32, wd2, d2b, lens, y3hi, y3lo, hb2hi, hb2lo,
        nullptr, nullptr, outp, nullptr, nullptr, nullptr, cnt + 192, cnt + 128, smem);
}

// ---------------- classifier ----------------
__global__ __launch_bounds__(256) void classifier_k(
    const float* __restrict__ h0f, const float* __restrict__ lw1,
    const float* __restrict__ lb1, const float* __restrict__ lw2,
    const float* __restrict__ lb2, float* __restrict__ lab) {
  __shared__ float h0s[H2];
  __shared__ float hid[H1];
  __shared__ float red0[4], red1[4];
  int b = blockIdx.x, tid = threadIdx.x;
  for (int i = tid; i < H2; i += 256) h0s[i] = h0f[(size_t)b * H2 + i];
  __syncthreads();
  {
    int j = tid;
    float a = lb1[j];
    #pragma unroll 4
    for (int k = 0; k < H2; ++k) a += h0s[k] * lw1[(size_t)j * H2 + k];
    hid[j] = a > 0.f ? a : 0.f;
  }
  __syncthreads();
  float p0 = hid[tid] * lw2[tid];
  float p1 = hid[tid] * lw2[H1 + tid];
  for (int o = 32; o > 0; o >>= 1) { p0 += __shfl_down(p0, o); p1 += __shfl_down(p1, o); }
  int lane = tid & 63, wave = tid >> 6;
  if (lane == 0) { red0[wave] = p0; red1[wave] = p1; }
  __syncthreads();
  if (tid == 0) {
    float z0 = red0[0] + red0[1] + red0[2] + red0[3] + lb2[0];
    float z1 = red1[0] + red1[1] + red1[2] + red1[3] + lb2[1];
    float mz = fmaxf(z0, z1);
    float l = mz + logf(__expf(z0 - mz) + __expf(z1 - mz));
    lab[b * 2 + 0] = z0 - l;
    lab[b * 2 + 1] = z1 - l;
  }
}

// ---------------- host smem mirror ----------------
static constexpr size_t smem_bytes(int In, int Hh, int P, bool CX) {
  size_t Jc = (size_t)Hh / P, R = 4 * Jc, NT = R / 16, K = (size_t)In + Hh;
  size_t PLANE = (K / 32) * NT * 512, WGS = 2 * PLANE;
  return A16(WGS * 2) + A16(64 * (R + 1) * 4) * (CX ? (size_t)2 : (size_t)1);
}

extern "C" void kernel_launch(void* const* d_in, const int* in_sizes, int n_in,
                              void* d_out, int out_size, void* d_ws, size_t ws_size,
                              hipStream_t stream) {
  (void)in_sizes; (void)n_in; (void)ws_size;
  const float* x      = (const float*)d_in[0];
  const int*   lens   = (const int*)d_in[1];
  const float* e1_wih = (const float*)d_in[2];
  const float* e1_whh = (const float*)d_in[3];
  const float* e1_b   = (const float*)d_in[4];
  const float* e2_wih = (const float*)d_in[5];
  const float* e2_whh = (const float*)d_in[6];
  const float* e2_b   = (const float*)d_in[7];
  const float* d1_wih = (const float*)d_in[8];
  const float* d1_whh = (const float*)d_in[9];
  const float* d1_b   = (const float*)d_in[10];
  const float* d2_wih = (const float*)d_in[11];
  const float* d2_whh = (const float*)d_in[12];
  const float* d2_b   = (const float*)d_in[13];
  const float* lw1    = (const float*)d_in[14];
  const float* lb1    = (const float*)d_in[15];
  const float* lw2    = (const float*)d_in[16];
  const float* lb2    = (const float*)d_in[17];

  char* ws = (char*)d_ws;
  u32*   cnt  = (u32*)(ws + OFF_CNT);
  short* xhi  = (short*)(ws + OFF_XHI);
  short* xlo  = (short*)(ws + OFF_XLO);
  short* y1hi = (short*)(ws + OFF_Y1HI);
  short* y1lo = (short*)(ws + OFF_Y1LO);
  short* y3hi = (short*)(ws + OFF_Y3HI);
  short* y3lo = (short*)(ws + OFF_Y3LO);
  short* hb1hi = (short*)(ws + OFF_HB1HI);
  short* hb1lo = (short*)(ws + OFF_HB1LO);
  short* hb2hi = (short*)(ws + OFF_HB2HI);
  short* hb2lo = (short*)(ws + OFF_HB2LO);
  short* h0hi = (short*)(ws + OFF_H0HI);
  short* h0lo = (short*)(ws + OFF_H0LO);
  float* h0f  = (float*)(ws + OFF_H0F);
  short* we1  = (short*)(ws + OFF_WE1);
  short* we2  = (short*)(ws + OFF_WE2);
  short* wd1  = (short*)(ws + OFF_WD1);
  short* wd2  = (short*)(ws + OFF_WD2);

  hipMemsetAsync(d_out, 0, (size_t)out_size * 4, stream);
  hipMemsetAsync(cnt, 0, 4096, stream);
  hipMemsetAsync(ws + OFF_HB1HI, 0, 4 * HBR, stream);

  pack_x_k<<<4096, 256, 0, stream>>>(x, xhi, xlo, XS);
  prep_w<IN0, H1, 32><<<1536, 256, 0, stream>>>(e1_wih, e1_whh, we1);
  prep_w<H1, H2, 64><<<6144, 256, 0, stream>>>(e2_wih, e2_whh, we2);
  prep_w<H2, H1, 32><<<3072, 256, 0, stream>>>(d1_wih, d1_whh, wd1);
  prep_w<H1, IN0, 32><<<768, 256, 0, stream>>>(d2_wih, d2_whh, wd2);

  constexpr size_t sE1 = smem_bytes(IN0, H1, 32, false);
  constexpr size_t sE2 = smem_bytes(H1, H2, 64, false);
  constexpr size_t sD1 = smem_bytes(H2, H1, 32, true);
  constexpr size_t sD2 = smem_bytes(H1, IN0, 32, false);
  constexpr size_t SA = sE1 > sE2 ? sE1 : sE2;
  constexpr size_t SB = sD1 > sD2 ? sD1 : sD2;

  hipFuncSetAttribute((const void*)phaseA_k, hipFuncAttributeMaxDynamicSharedMemorySize, (int)SA);
  hipFuncSetAttribute((const void*)phaseB_k, hipFuncAttributeMaxDynamicSharedMemorySize, (int)SB);

  phaseA_k<<<96, 256, SA, stream>>>(we1, e1_b, we2, e2_b, lens, xhi, xlo,
                                    y1hi, y1lo, hb1hi, hb1lo, hb2hi, hb2lo,
                                    h0hi, h0lo, h0f, cnt);
  classifier_k<<<64, 256, 0, stream>>>(h0f, lw1, lb1, lw2, lb2, (float*)d_out + OUT_ELEMS);
  hipMemsetAsync(ws + OFF_HB1HI, 0, 4 * HBR, stream);
  phaseB_k<<<64, 256, SB, stream>>>(wd1, d1_b, wd2, d2_b, lens, h0hi, h0lo,
                                    y3hi, y3lo, hb1hi, hb1lo, hb2hi, hb2lo,
                                    (float*)d_out, cnt);
}

// Round 10
// 7484.766 us; speedup vs baseline: 1.1743x; 1.1743x over previous
//
#include <hip/hip_runtime.h>
#include <cstdint>
#include <cstddef>

typedef short short8 __attribute__((ext_vector_type(8)));
typedef float f32x4 __attribute__((ext_vector_type(4)));
typedef unsigned int u32;
typedef unsigned short u16;

#define DEV __device__ __forceinline__

// problem dims
constexpr int BB = 64, TT = 512, IN0 = 128, H1 = 256, H2 = 512;
constexpr size_t OUT_ELEMS = (size_t)BB * TT * IN0;  // 4194304

constexpr size_t ALB(size_t x) { return (x + 255) & ~(size_t)255; }
constexpr size_t A16(size_t x) { return (x + 15) & ~(size_t)15; }

// ---------------- workspace layout (bytes) ----------------
constexpr size_t XS  = (size_t)BB * TT * IN0;
constexpr size_t Y1S = (size_t)BB * TT * H1;
constexpr size_t HBR = (size_t)2 * BB * H2 * 2;                 // one hb plane (sized for H2)
// flag region: per-WG u32 flags at 16B spacing. e1@+0, e2@+1024B, d1@+2048B, d2@+3072B
constexpr size_t OFF_FLG  = 0;
constexpr size_t OFF_XHI  = 4096;
constexpr size_t OFF_XLO  = ALB(OFF_XHI + XS * 2);
constexpr size_t OFF_Y1HI = ALB(OFF_XLO + XS * 2);
constexpr size_t OFF_Y1LO = ALB(OFF_Y1HI + Y1S * 2);
constexpr size_t OFF_Y3HI = ALB(OFF_Y1LO + Y1S * 2);
constexpr size_t OFF_Y3LO = ALB(OFF_Y3HI + Y1S * 2);
constexpr size_t OFF_HB1HI = ALB(OFF_Y3LO + Y1S * 2);           // 4 contiguous hb planes
constexpr size_t OFF_HB1LO = OFF_HB1HI + HBR;
constexpr size_t OFF_HB2HI = OFF_HB1LO + HBR;
constexpr size_t OFF_HB2LO = OFF_HB2HI + HBR;
constexpr size_t OFF_H0HI = ALB(OFF_HB2LO + HBR);
constexpr size_t OFF_H0LO = ALB(OFF_H0HI + (size_t)BB * H2 * 2);
constexpr size_t OFF_H0F  = ALB(OFF_H0LO + (size_t)BB * H2 * 2);
constexpr size_t OFF_WE1  = ALB(OFF_H0F + (size_t)BB * H2 * 4);
constexpr size_t W_E1S = (size_t)4 * H1 * (IN0 + H1) * 2;       // shorts incl. both planes
constexpr size_t OFF_WE2  = ALB(OFF_WE1 + W_E1S * 2);
constexpr size_t W_E2S = (size_t)4 * H2 * (H1 + H2) * 2;
constexpr size_t OFF_WD1  = ALB(OFF_WE2 + W_E2S * 2);
constexpr size_t W_D1S = (size_t)4 * H1 * (H2 + H1) * 2;
constexpr size_t OFF_WD2  = ALB(OFF_WD1 + W_D1S * 2);

// ---------------- helpers ----------------
DEV void split32(float v, u16& hi, u16& lo) {
  u32 u = __builtin_bit_cast(u32, v);
  hi = (u16)(u >> 16);
  float hif = __builtin_bit_cast(float, u & 0xFFFF0000u);
  lo = (u16)(__builtin_bit_cast(u32, v - hif) >> 16);
}

DEV f32x4 mm(short8 a, short8 b, f32x4 c) {
  return __builtin_amdgcn_mfma_f32_16x16x32_bf16(a, b, c, 0, 0, 0);
}

DEV float sigm(float x) { return 1.f / (1.f + __expf(-x)); }
DEV float tanh_f(float x) { return 1.f - 2.f / (__expf(2.f * x) + 1.f); }

// Coherent (L1/L2-bypassing) ops — served at LLC, no fences needed.
DEV void ldg16c(short8& d, const short* p) {
  asm volatile("global_load_dwordx4 %0, %1, off sc0 sc1" : "=v"(d) : "v"(p));
}
DEV void stg4c(u32* p, u32 v) {
  asm volatile("global_store_dword %0, %1, off sc0 sc1" :: "v"(p), "v"(v) : "memory");
}

// group-issue N chunk pairs (2 dwordx4 each)
template<int N>
DEV void grp_issue(short8 (&h)[N], short8 (&l)[N], const short* ph, const short* pl) {
  #pragma unroll
  for (int i = 0; i < N; ++i) { ldg16c(h[i], ph + i * 32); ldg16c(l[i], pl + i * 32); }
}

#define TIE16(h, l) \
  "+v"(h[0]), "+v"(h[1]), "+v"(h[2]), "+v"(h[3]), "+v"(h[4]), "+v"(h[5]), "+v"(h[6]), "+v"(h[7]), \
  "+v"(l[0]), "+v"(l[1]), "+v"(l[2]), "+v"(l[3]), "+v"(l[4]), "+v"(l[5]), "+v"(l[6]), "+v"(l[7])

DEV void wt16_c0(short8 (&h)[8], short8 (&l)[8]) {
  asm volatile("s_waitcnt vmcnt(0)" : TIE16(h, l) :: "memory");
  __builtin_amdgcn_sched_barrier(0);
}
DEV void wt16_c8(short8 (&h)[8], short8 (&l)[8]) {
  asm volatile("s_waitcnt vmcnt(8)" : TIE16(h, l) :: "memory");
  __builtin_amdgcn_sched_barrier(0);
}
DEV void wt16_c16(short8 (&h)[8], short8 (&l)[8]) {
  asm volatile("s_waitcnt vmcnt(16)" : TIE16(h, l) :: "memory");
  __builtin_amdgcn_sched_barrier(0);
}
DEV void wt8_c0(short8 (&h)[4], short8 (&l)[4]) {
  asm volatile("s_waitcnt vmcnt(0)"
               : "+v"(h[0]), "+v"(h[1]), "+v"(h[2]), "+v"(h[3]),
                 "+v"(l[0]), "+v"(l[1]), "+v"(l[2]), "+v"(l[3]) :: "memory");
  __builtin_amdgcn_sched_barrier(0);
}

// Wave-0 flag poll: per-WG monotone flags at 16B spacing (8 flags / 128B line).
// Lane i gathers flag[i&(P-1)] (own) and flag[i&(UPP-1)] (up) -> 4-8 parallel
// line RTs, no RMW anywhere. s_sleep backoff keeps the lines cool.
template<int P, int UPP>
DEV void pollf(const u32* own, u32 othr, const u32* up, u32 uthr, int lane) {
  const u32* po = own + (size_t)(lane & (P - 1)) * 4;
  const u32* pu = up + (size_t)(lane & (UPP - 1)) * 4;
  while (true) {
    u32 a, b;
    asm volatile("global_load_dword %0, %2, off sc0 sc1\n\t"
                 "global_load_dword %1, %3, off sc0 sc1\n\t"
                 "s_waitcnt vmcnt(0)"
                 : "=v"(a), "=v"(b) : "v"(po), "v"(pu) : "memory");
    if (__all(a >= othr && b >= uthr)) return;
    __builtin_amdgcn_s_sleep(1);
  }
}

template<int NTv>
DEV void store_tile(float* dst, const f32x4* acc, int lane, int wave, int RS_) {
  #pragma unroll
  for (int nt = 0; nt < NTv; ++nt)
    #pragma unroll
    for (int r = 0; r < 4; ++r)
      dst[(wave * 16 + (lane >> 4) * 4 + r) * RS_ + nt * 16 + (lane & 15)] = acc[nt][r];
}

template<int NTv, int PLANEv, int NCH>
DEV void mfma_grp(f32x4 (&acc)[NTv], const short8* ha, const short8* la,
                  int cbase, const short* wlds, int lane) {
  #pragma unroll
  for (int cc = 0; cc < NCH; ++cc) {
    const int c = cbase + cc;
    #pragma unroll
    for (int nt = 0; nt < NTv; ++nt) {
      const int fo = ((c * NTv + nt) * 64 + lane) * 8;
      short8 bh = *(const short8*)(wlds + fo);
      short8 bl = *(const short8*)(wlds + PLANEv + fo);
      acc[nt] = mm(ha[cc], bh, acc[nt]);
      acc[nt] = mm(la[cc], bh, acc[nt]);
      acc[nt] = mm(ha[cc], bl, acc[nt]);
    }
  }
}

// ---------------- prep kernels ----------------
__global__ void pack_x_k(const float* __restrict__ src, short* __restrict__ hp,
                         short* __restrict__ lp, size_t n) {
  for (size_t i = (size_t)blockIdx.x * blockDim.x + threadIdx.x; i < n;
       i += (size_t)gridDim.x * blockDim.x) {
    u16 hi, lo; split32(src[i], hi, lo);
    hp[i] = (short)hi; lp[i] = (short)lo;
  }
}

template<int In, int Hh, int P>
__global__ void prep_w(const float* __restrict__ wih, const float* __restrict__ whh,
                       short* __restrict__ dst) {
  constexpr int Jc = Hh / P, R = 4 * Jc, NT = R / 16, K = In + Hh;
  constexpr int NC32 = K / 32, PLANE = NC32 * NT * 512, WGS = 2 * PLANE;
  const size_t total = (size_t)P * PLANE;
  for (size_t s = (size_t)blockIdx.x * blockDim.x + threadIdx.x; s < total;
       s += (size_t)gridDim.x * blockDim.x) {
    int p   = (int)(s / PLANE);
    int r2  = (int)(s % PLANE);
    int c32 = r2 / (NT * 512);
    int r3  = r2 % (NT * 512);
    int nt  = r3 / 512;
    int sl  = r3 % 512;
    int lane = sl / 8, j = sl % 8;
    int n  = nt * 16 + (lane & 15);
    int g  = n / Jc, jl = n % Jc;
    int grow = g * Hh + p * Jc + jl;
    int k = c32 * 32 + (lane >> 4) * 8 + j;
    float v = (k < In) ? wih[(size_t)grow * In + k] : whh[(size_t)grow * Hh + (k - In)];
    u16 hi, lo; split32(v, hi, lo);
    dst[(size_t)p * WGS + r2]         = (short)hi;
    dst[(size_t)p * WGS + PLANE + r2] = (short)lo;
  }
}

// ---------------- persistent LSTM layer body ----------------
// Flag-sync, ping-pong depth 2. At step t a WG requires:
//   all own-layer flags >= t    (peers finished t-1 -> h(t) published, and
//                                buffer (t+1)&1 is safe to overwrite)
//   all upstream flags >= t+1   (upstream finished step t -> y(t) published)
// After publishing, drain stores (vmcnt 0), __syncthreads, tid0 stores its
// own flag = t+1 (plain sc0sc1 store, monotone, no RMW). Only wave 0 polls.
template<int In, int Hh, int P, int UP, bool CX, bool COHX, bool WY, bool WO, bool WH0>
DEV void lstm_body(int p, const short* __restrict__ wfrag, const float* __restrict__ bias,
                   const int* __restrict__ lengths,
                   const short* xhi, const short* xlo,
                   short* hbhi, short* hblo,
                   short* yhi, short* ylo, float* outp,
                   short* h0hi, short* h0lo, float* h0f,
                   u32* ownf, const u32* upf, char* smem) {
  constexpr int Jc = Hh / P, R = 4 * Jc, NT = R / 16, K = In + Hh;
  constexpr int NC32 = K / 32, C0 = In / 32, HC = Hh / 32;
  constexpr int PLANE = NC32 * NT * 512, WGS = 2 * PLANE;
  constexpr int RS = R + 1;
  constexpr int JH = Jc / 2, NP = 64 * JH;
  constexpr int UPP = (UP > 0) ? UP : P;
  static_assert(R % 16 == 0 && K % 32 == 0 && In % 32 == 0 && Jc % 2 == 0 && NP <= 256, "geometry");

  constexpr size_t SM_W = A16((size_t)WGS * 2);
  constexpr size_t SM_G = A16((size_t)64 * RS * 4);
  short* wlds  = (short*)smem;
  float* gates = (float*)(smem + SM_W);
  float* gx    = (float*)(smem + SM_W + SM_G);   // only when CX

  const int tid = threadIdx.x;
  const int lane = tid & 63, wave = tid >> 6;
  const int j0 = p * Jc;
  const int m = wave * 16 + (lane & 15);         // batch this lane supplies to A-frags
  const int klane = (lane >> 4) * 8;
  const size_t BH = (size_t)BB * Hh;

  // stage weights (linear copy; already in fragment order)
  {
    const uint4* src = (const uint4*)(wfrag + (size_t)p * WGS);
    uint4* dv = (uint4*)wlds;
    for (int i = tid; i < WGS / 8; i += 256) dv[i] = src[i];
  }

  // persistent per-thread recurrent state (one jl-pair of one batch)
  const bool actv = tid < NP;
  int b = 0, jl = 0, mylen = 0;
  float cc0 = 0.f, cc1 = 0.f, hh0 = 0.f, hh1 = 0.f;
  float bi0 = 0, bi1 = 0, bf0 = 0, bf1 = 0, bg0 = 0, bg1 = 0, bo0 = 0, bo1 = 0;
  if (actv) {
    b = tid / JH; jl = (tid % JH) * 2;
    mylen = lengths[b];
    bi0 = bias[0 * Hh + j0 + jl]; bi1 = bias[0 * Hh + j0 + jl + 1];
    bf0 = bias[1 * Hh + j0 + jl]; bf1 = bias[1 * Hh + j0 + jl + 1];
    bg0 = bias[2 * Hh + j0 + jl]; bg1 = bias[2 * Hh + j0 + jl + 1];
    bo0 = bias[3 * Hh + j0 + jl]; bo1 = bias[3 * Hh + j0 + jl + 1];
  }

  __syncthreads();  // wlds staged (CX prologue below reads it!)

  // constant input projection (decoder-1: dec_in = h0 for all valid t)
  if constexpr (CX) {
    f32x4 acc[NT];
    #pragma unroll
    for (int nt = 0; nt < NT; ++nt) acc[nt] = f32x4{0.f, 0.f, 0.f, 0.f};
    #pragma unroll
    for (int c = 0; c < C0; ++c) {
      size_t idx = (size_t)m * In + c * 32 + klane;
      short8 ah = *(const short8*)(xhi + idx);
      short8 al = *(const short8*)(xlo + idx);
      #pragma unroll
      for (int nt = 0; nt < NT; ++nt) {
        int fo = ((c * NT + nt) * 64 + lane) * 8;
        short8 bh = *(const short8*)(wlds + fo);
        short8 bl = *(const short8*)(wlds + PLANE + fo);
        acc[nt] = mm(ah, bh, acc[nt]);
        acc[nt] = mm(al, bh, acc[nt]);
        acc[nt] = mm(ah, bl, acc[nt]);
      }
    }
    store_tile<NT>(gx, acc, lane, wave, RS);
    __syncthreads();
  }

  for (int t = 0; t < TT; ++t) {
    const int cur = t & 1, nxt = cur ^ 1;
    if (wave == 0) {
      if constexpr (UP > 0) pollf<P, UPP>(ownf, (u32)t, upf, (u32)(t + 1), lane);
      else                  pollf<P, UPP>(ownf, (u32)t, ownf, (u32)t, lane);
    }
    __syncthreads();

    f32x4 acc[NT];
    #pragma unroll
    for (int nt = 0; nt < NT; ++nt) acc[nt] = f32x4{0.f, 0.f, 0.f, 0.f};

    const short* hph = hbhi + (size_t)cur * BH + (size_t)m * Hh + klane;
    const short* hpl = hblo + (size_t)cur * BH + (size_t)m * Hh + klane;

    if constexpr (!CX && !COHX) {
      // e1: plain cached x loads (input produced by a previous kernel)
      #pragma unroll
      for (int c = 0; c < C0; ++c) {
        size_t idx = ((size_t)m * TT + t) * In + c * 32 + klane;
        short8 ah = *(const short8*)(xhi + idx);
        short8 al = *(const short8*)(xlo + idx);
        #pragma unroll
        for (int nt = 0; nt < NT; ++nt) {
          int fo = ((c * NT + nt) * 64 + lane) * 8;
          short8 bh = *(const short8*)(wlds + fo);
          short8 bl = *(const short8*)(wlds + PLANE + fo);
          acc[nt] = mm(ah, bh, acc[nt]);
          acc[nt] = mm(al, bh, acc[nt]);
          acc[nt] = mm(ah, bl, acc[nt]);
        }
      }
    }

    if constexpr (COHX) {
      static_assert(C0 == 8, "cohx geometry");
      const short* pxh = xhi + ((size_t)m * TT + t) * In + klane;
      const short* pxl = xlo + ((size_t)m * TT + t) * In + klane;
      short8 xh[8], xl[8];
      grp_issue<8>(xh, xl, pxh, pxl);
      if constexpr (HC == 16) {       // e2
        short8 h1h[8], h1l[8];
        grp_issue<8>(h1h, h1l, hph, hpl);
        wt16_c16(xh, xl);
        mfma_grp<NT, PLANE, 8>(acc, xh, xl, 0, wlds, lane);
        short8 h2h[8], h2l[8];
        grp_issue<8>(h2h, h2l, hph + 256, hpl + 256);
        wt16_c16(h1h, h1l);
        mfma_grp<NT, PLANE, 8>(acc, h1h, h1l, C0, wlds, lane);
        wt16_c0(h2h, h2l);
        mfma_grp<NT, PLANE, 8>(acc, h2h, h2l, C0 + 8, wlds, lane);
      } else {                        // d2 (HC == 4)
        static_assert(HC == 4, "d2 geometry");
        short8 hh4[4], hl4[4];
        grp_issue<4>(hh4, hl4, hph, hpl);
        wt16_c8(xh, xl);
        mfma_grp<NT, PLANE, 8>(acc, xh, xl, 0, wlds, lane);
        wt8_c0(hh4, hl4);
        mfma_grp<NT, PLANE, 4>(acc, hh4, hl4, C0, wlds, lane);
      }
    } else {
      static_assert(HC == 8, "h geometry");
      short8 hh8[8], hl8[8];
      grp_issue<8>(hh8, hl8, hph, hpl);
      wt16_c0(hh8, hl8);
      mfma_grp<NT, PLANE, 8>(acc, hh8, hl8, C0, wlds, lane);
    }

    store_tile<NT>(gates, acc, lane, wave, RS);
    __syncthreads();

    if (actv) {
      const int gb = b * RS;
      float gi0 = gates[gb + 0 * Jc + jl] + bi0, gi1 = gates[gb + 0 * Jc + jl + 1] + bi1;
      float gf0 = gates[gb + 1 * Jc + jl] + bf0, gf1 = gates[gb + 1 * Jc + jl + 1] + bf1;
      float gg0 = gates[gb + 2 * Jc + jl] + bg0, gg1 = gates[gb + 2 * Jc + jl + 1] + bg1;
      float go0 = gates[gb + 3 * Jc + jl] + bo0, go1 = gates[gb + 3 * Jc + jl + 1] + bo1;
      if constexpr (CX) {
        gi0 += gx[gb + 0 * Jc + jl]; gi1 += gx[gb + 0 * Jc + jl + 1];
        gf0 += gx[gb + 1 * Jc + jl]; gf1 += gx[gb + 1 * Jc + jl + 1];
        gg0 += gx[gb + 2 * Jc + jl]; gg1 += gx[gb + 2 * Jc + jl + 1];
        go0 += gx[gb + 3 * Jc + jl]; go1 += gx[gb + 3 * Jc + jl + 1];
      }
      bool valid = t < mylen;
      float cn0 = sigm(gf0) * cc0 + sigm(gi0) * tanh_f(gg0);
      float hn0 = sigm(go0) * tanh_f(cn0);
      float cn1 = sigm(gf1) * cc1 + sigm(gi1) * tanh_f(gg1);
      float hn1 = sigm(go1) * tanh_f(cn1);
      if (valid) { cc0 = cn0; hh0 = hn0; cc1 = cn1; hh1 = hn1; }
      u16 p0h, p0l, p1h, p1l;
      split32(hh0, p0h, p0l); split32(hh1, p1h, p1l);
      u32 whi = (u32)p0h | ((u32)p1h << 16);
      u32 wlo = (u32)p0l | ((u32)p1l << 16);
      size_t wi = ((size_t)b * Hh + j0 + jl) >> 1;
      stg4c((u32*)(hbhi + (size_t)nxt * BH) + wi, whi);
      stg4c((u32*)(hblo + (size_t)nxt * BH) + wi, wlo);
      if constexpr (WY) {
        if (valid) {
          size_t yo = ((size_t)b * TT + t) * Hh + j0 + jl;
          stg4c((u32*)(yhi + yo), whi);
          stg4c((u32*)(ylo + yo), wlo);
        }
      }
      if constexpr (WO) {
        if (valid) {
          size_t oo = ((size_t)b * TT + t) * Hh + j0 + jl;
          outp[oo] = hh0; outp[oo + 1] = hh1;
        }
      }
    }
    asm volatile("s_waitcnt vmcnt(0)" ::: "memory");  // all publishes ack'd at LLC
    __syncthreads();
    if (tid == 0) stg4c(ownf + (size_t)p * 4, (u32)(t + 1));
  }

  if constexpr (WH0) {
    if (actv) {
      u16 p0h, p0l, p1h, p1l;
      split32(hh0, p0h, p0l); split32(hh1, p1h, p1l);
      size_t o = (size_t)b * Hh + j0 + jl;
      h0hi[o] = (short)p0h; h0hi[o + 1] = (short)p1h;
      h0lo[o] = (short)p0l; h0lo[o + 1] = (short)p1l;
      h0f[o] = hh0; h0f[o + 1] = hh1;
    }
  }
}

// ---------------- fused phase kernels ----------------
__global__ __launch_bounds__(256, 1) void phaseA_k(
    const short* we1, const float* e1b, const short* we2, const float* e2b,
    const int* lens, const short* xhi, const short* xlo,
    short* y1hi, short* y1lo,
    short* hb1hi, short* hb1lo, short* hb2hi, short* hb2lo,
    short* h0hi, short* h0lo, float* h0f, u32* flg) {
  extern __shared__ char smem[];
  if (blockIdx.x < 32)
    lstm_body<IN0, H1, 32, 0, false, false, true, false, false>(
        blockIdx.x, we1, e1b, lens, xhi, xlo, hb1hi, hb1lo,
        y1hi, y1lo, nullptr, nullptr, nullptr, nullptr, flg, nullptr, smem);
  else
    lstm_body<H1, H2, 64, 32, false, true, false, false, true>(
        blockIdx.x - 32, we2, e2b, lens, y1hi, y1lo, hb2hi, hb2lo,
        nullptr, nullptr, nullptr, h0hi, h0lo, h0f, flg + 256, flg, smem);
}

__global__ __launch_bounds__(256, 1) void phaseB_k(
    const short* wd1, const float* d1b, const short* wd2, const float* d2b,
    const int* lens, const short* h0hi_in, const short* h0lo_in,
    short* y3hi, short* y3lo,
    short* hb1hi, short* hb1lo, short* hb2hi, short* hb2lo,
    float* outp, u32* flg) {
  extern __shared__ char smem[];
  if (blockIdx.x < 32)
    lstm_body<H2, H1, 32, 0, true, false, true, false, false>(
        blockIdx.x, wd1, d1b, lens, h0hi_in, h0lo_in, hb1hi, hb1lo,
        y3hi, y3lo, nullptr, nullptr, nullptr, nullptr, flg + 512, nullptr, smem);
  else
    lstm_body<H1, IN0, 32, 32, false, true, false, true, false>(
        blockIdx.x - 32, wd2, d2b, lens, y3hi, y3lo, hb2hi, hb2lo,
        nullptr, nullptr, outp, nullptr, nullptr, nullptr, flg + 768, flg + 512, smem);
}

// ---------------- classifier ----------------
__global__ __launch_bounds__(256) void classifier_k(
    const float* __restrict__ h0f, const float* __restrict__ lw1,
    const float* __restrict__ lb1, const float* __restrict__ lw2,
    const float* __restrict__ lb2, float* __restrict__ lab) {
  __shared__ float h0s[H2];
  __shared__ float hid[H1];
  __shared__ float red0[4], red1[4];
  int b = blockIdx.x, tid = threadIdx.x;
  for (int i = tid; i < H2; i += 256) h0s[i] = h0f[(size_t)b * H2 + i];
  __syncthreads();
  {
    int j = tid;
    float a = lb1[j];
    #pragma unroll 4
    for (int k = 0; k < H2; ++k) a += h0s[k] * lw1[(size_t)j * H2 + k];
    hid[j] = a > 0.f ? a : 0.f;
  }
  __syncthreads();
  float p0 = hid[tid] * lw2[tid];
  float p1 = hid[tid] * lw2[H1 + tid];
  for (int o = 32; o > 0; o >>= 1) { p0 += __shfl_down(p0, o); p1 += __shfl_down(p1, o); }
  int lane = tid & 63, wave = tid >> 6;
  if (lane == 0) { red0[wave] = p0; red1[wave] = p1; }
  __syncthreads();
  if (tid == 0) {
    float z0 = red0[0] + red0[1] + red0[2] + red0[3] + lb2[0];
    float z1 = red1[0] + red1[1] + red1[2] + red1[3] + lb2[1];
    float mz = fmaxf(z0, z1);
    float l = mz + logf(__expf(z0 - mz) + __expf(z1 - mz));
    lab[b * 2 + 0] = z0 - l;
    lab[b * 2 + 1] = z1 - l;
  }
}

// ---------------- host smem mirror ----------------
static constexpr size_t smem_bytes(int In, int Hh, int P, bool CX) {
  size_t Jc = (size_t)Hh / P, R = 4 * Jc, NT = R / 16, K = (size_t)In + Hh;
  size_t PLANE = (K / 32) * NT * 512, WGS = 2 * PLANE;
  return A16(WGS * 2) + A16(64 * (R + 1) * 4) * (CX ? (size_t)2 : (size_t)1);
}

extern "C" void kernel_launch(void* const* d_in, const int* in_sizes, int n_in,
                              void* d_out, int out_size, void* d_ws, size_t ws_size,
                              hipStream_t stream) {
  (void)in_sizes; (void)n_in; (void)ws_size;
  const float* x      = (const float*)d_in[0];
  const int*   lens   = (const int*)d_in[1];
  const float* e1_wih = (const float*)d_in[2];
  const float* e1_whh = (const float*)d_in[3];
  const float* e1_b   = (const float*)d_in[4];
  const float* e2_wih = (const float*)d_in[5];
  const float* e2_whh = (const float*)d_in[6];
  const float* e2_b   = (const float*)d_in[7];
  const float* d1_wih = (const float*)d_in[8];
  const float* d1_whh = (const float*)d_in[9];
  const float* d1_b   = (const float*)d_in[10];
  const float* d2_wih = (const float*)d_in[11];
  const float* d2_whh = (const float*)d_in[12];
  const float* d2_b   = (const float*)d_in[13];
  const float* lw1    = (const float*)d_in[14];
  const float* lb1    = (const float*)d_in[15];
  const float* lw2    = (const float*)d_in[16];
  const float* lb2    = (const float*)d_in[17];

  char* ws = (char*)d_ws;
  u32*   flg  = (u32*)(ws + OFF_FLG);
  short* xhi  = (short*)(ws + OFF_XHI);
  short* xlo  = (short*)(ws + OFF_XLO);
  short* y1hi = (short*)(ws + OFF_Y1HI);
  short* y1lo = (short*)(ws + OFF_Y1LO);
  short* y3hi = (short*)(ws + OFF_Y3HI);
  short* y3lo = (short*)(ws + OFF_Y3LO);
  short* hb1hi = (short*)(ws + OFF_HB1HI);
  short* hb1lo = (short*)(ws + OFF_HB1LO);
  short* hb2hi = (short*)(ws + OFF_HB2HI);
  short* hb2lo = (short*)(ws + OFF_HB2LO);
  short* h0hi = (short*)(ws + OFF_H0HI);
  short* h0lo = (short*)(ws + OFF_H0LO);
  float* h0f  = (float*)(ws + OFF_H0F);
  short* we1  = (short*)(ws + OFF_WE1);
  short* we2  = (short*)(ws + OFF_WE2);
  short* wd1  = (short*)(ws + OFF_WD1);
  short* wd2  = (short*)(ws + OFF_WD2);

  hipMemsetAsync(d_out, 0, (size_t)out_size * 4, stream);
  hipMemsetAsync(flg, 0, 4096, stream);
  hipMemsetAsync(ws + OFF_HB1HI, 0, 4 * HBR, stream);

  pack_x_k<<<4096, 256, 0, stream>>>(x, xhi, xlo, XS);
  prep_w<IN0, H1, 32><<<1536, 256, 0, stream>>>(e1_wih, e1_whh, we1);
  prep_w<H1, H2, 64><<<6144, 256, 0, stream>>>(e2_wih, e2_whh, we2);
  prep_w<H2, H1, 32><<<3072, 256, 0, stream>>>(d1_wih, d1_whh, wd1);
  prep_w<H1, IN0, 32><<<768, 256, 0, stream>>>(d2_wih, d2_whh, wd2);

  constexpr size_t sE1 = smem_bytes(IN0, H1, 32, false);
  constexpr size_t sE2 = smem_bytes(H1, H2, 64, false);
  constexpr size_t sD1 = smem_bytes(H2, H1, 32, true);
  constexpr size_t sD2 = smem_bytes(H1, IN0, 32, false);
  constexpr size_t SA = sE1 > sE2 ? sE1 : sE2;
  constexpr size_t SB = sD1 > sD2 ? sD1 : sD2;

  hipFuncSetAttribute((const void*)phaseA_k, hipFuncAttributeMaxDynamicSharedMemorySize, (int)SA);
  hipFuncSetAttribute((const void*)phaseB_k, hipFuncAttributeMaxDynamicSharedMemorySize, (int)SB);

  phaseA_k<<<96, 256, SA, stream>>>(we1, e1_b, we2, e2_b, lens, xhi, xlo,
                                    y1hi, y1lo, hb1hi, hb1lo, hb2hi, hb2lo,
                                    h0hi, h0lo, h0f, flg);
  // hb planes must be re-zeroed for phaseB (d1/d2 expect h(0)=0; phaseA left
  // e1/e2 final states here). Round-7 regression: this memset was missing.
  hipMemsetAsync(ws + OFF_HB1HI, 0, 4 * HBR, stream);
  phaseB_k<<<64, 256, SB, stream>>>(wd1, d1_b, wd2, d2_b, lens, h0hi, h0lo,
                                    y3hi, y3lo, hb1hi, hb1lo, hb2hi, hb2lo,
                                    (float*)d_out, flg);
  classifier_k<<<64, 256, 0, stream>>>(h0f, lw1, lb1, lw2, lb2, (float*)d_out + OUT_ELEMS);
}